// Round 13
// baseline (39.700 us; speedup 1.0000x reference)
//
#include <hip/hip_runtime.h>
#include <math.h>

namespace {

constexpr int N  = 4096;
constexpr int E  = 256;
constexpr int H  = 8;
constexpr int DH = 32;
constexpr int BS = 8;
// fold 1/sqrt(DH) and log2(e): softmax in exp2 domain, no max subtraction
// (f32-safe: |s*CL| realistic max ~16, overflow at 127 -> 27 sigma margin)
constexpr float CL = 0.17677669529663687f * 1.4426950408889634f;

typedef __bf16 bf16x8 __attribute__((ext_vector_type(8)));
typedef __bf16 bf16x4 __attribute__((ext_vector_type(4)));
typedef float  f32x4  __attribute__((ext_vector_type(4)));

#if __has_builtin(__builtin_amdgcn_exp2f)
#define EXP2F(x) __builtin_amdgcn_exp2f(x)
#else
#define EXP2F(x) __expf((x) * 0.6931471805599453f)
#endif

__device__ inline bf16x8 pack8(float4 a, float4 b) {
  bf16x8 r;
  r[0] = (__bf16)a.x; r[1] = (__bf16)a.y; r[2] = (__bf16)a.z; r[3] = (__bf16)a.w;
  r[4] = (__bf16)b.x; r[5] = (__bf16)b.y; r[6] = (__bf16)b.z; r[7] = (__bf16)b.w;
  return r;
}

// ===========================================================================
// FRAGMENT-MAJOR LAYOUTS (proven round 12: 68.7 -> 38.5 us):
// every MFMA operand lives in memory as [frag][lane(64)][elem(8)] so the
// consuming wave loads it as ONE coalesced 1KB instruction (16B/lane).
//   xpe/xv : frag_id = rowtile(256)*8 + ktile(8)
//   wfrag  : per mat, frag_id = n16(16)*8 + ktile
//   qfrag  : frag_id = head*256 + rowtile
//   kfrag  : frag_id = (head*64 + keytile64)*4 + mt  (key-ID perm baked in)
//   vfrag  : frag_id = ((head*64+keytile64)*2+ks)*2+dh
// ===========================================================================

// ---------------------------------------------------------------------------
// prep: fragment-major bf16 conversion of x+pe, x, and the 4 weight mats.
// (frozen from round 12)
// ---------------------------------------------------------------------------
__global__ __launch_bounds__(256) void prep_kernel(
    const float* __restrict__ x, const float* __restrict__ pe,
    const int* __restrict__ xb,
    const float* __restrict__ Wq, const float* __restrict__ Wk,
    const float* __restrict__ Wv, const float* __restrict__ Wo,
    __bf16* __restrict__ xpef, __bf16* __restrict__ xvf,
    __bf16* __restrict__ wfrag, int* __restrict__ seg)
{
  const int bid  = blockIdx.x;
  const int wv4  = threadIdx.x >> 6;
  const int lane = threadIdx.x & 63;
  const int l15  = lane & 15, g = lane >> 4;

  if (bid < 512) {
    const int wid = bid * 4 + wv4;            // = rt*8 + kt
    const int rt = wid >> 3, kt = wid & 7;
    const float* xr = x  + (size_t)(rt * 16 + l15) * E + kt * 32 + 8 * g;
    const float* pr = pe + (size_t)(rt * 16 + l15) * E + kt * 32 + 8 * g;
    float4 a0 = *(const float4*)xr;
    float4 a1 = *(const float4*)(xr + 4);
    const float4 p0 = *(const float4*)pr;
    const float4 p1 = *(const float4*)(pr + 4);
    *reinterpret_cast<bf16x8*>(xvf + (size_t)wid * 512 + lane * 8) = pack8(a0, a1);
    a0.x += p0.x; a0.y += p0.y; a0.z += p0.z; a0.w += p0.w;
    a1.x += p1.x; a1.y += p1.y; a1.z += p1.z; a1.w += p1.w;
    *reinterpret_cast<bf16x8*>(xpef + (size_t)wid * 512 + lane * 8) = pack8(a0, a1);
  } else if (bid < 640) {
    const int wid = (bid - 512) * 4 + wv4;    // [0,512)
    const int mat = wid >> 7;
    const int rem = wid & 127;                // n16*8 + kt
    const int n16 = rem >> 3, kt = rem & 7;
    const float* __restrict__ W =
        (mat == 0) ? Wq : (mat == 1) ? Wk : (mat == 2) ? Wv : Wo;
    const float* wr = W + (size_t)(n16 * 16 + l15) * E + kt * 32 + 8 * g;
    *reinterpret_cast<bf16x8*>(wfrag + (size_t)wid * 512 + lane * 8) =
        pack8(*(const float4*)wr, *(const float4*)(wr + 4));
  } else {
    if (threadIdx.x <= BS) {
      const int t = threadIdx.x;
      int lo = 0, hi = N;
      while (lo < hi) { int mid = (lo + hi) >> 1; if (xb[mid] < t) lo = mid + 1; else hi = mid; }
      seg[t] = lo;
    }
  }
}

// ---------------------------------------------------------------------------
// MFMA QKV from fragment-major operands, W-window prefetch.
// Block = 16 rows x 128 cols, 4 waves (32-col slices), grid (512,3).
// The fully-unrolled kk loop keeps a 4-slot rotating window of W fragments
// (2 kk-steps = ~4 loads in flight) so the compiler can't sink the loads
// back to their use sites (the r4-r9 latency-queue failure mode).
// ---------------------------------------------------------------------------
__global__ __launch_bounds__(256) void qkv_mfma(
    const __bf16* __restrict__ xpef, const __bf16* __restrict__ xvf,
    const __bf16* __restrict__ wfrag,
    const float* __restrict__ bq, const float* __restrict__ bk,
    const float* __restrict__ bv,
    __bf16* __restrict__ qfrag, __bf16* __restrict__ kfrag,
    __bf16* __restrict__ vfrag)
{
  const int mat  = blockIdx.y;
  const int rt   = blockIdx.x >> 1;
  const int half = blockIdx.x & 1;
  const int wv   = threadIdx.x >> 6;
  const int lane = threadIdx.x & 63;
  const int l15  = lane & 15, g = lane >> 4;
  const int m0   = rt * 16;
  const int cb0  = half * 128 + wv * 32;

  const __bf16* __restrict__ A = (mat < 2) ? xpef : xvf;
  const __bf16* __restrict__ W = wfrag + (size_t)mat * 65536;

  bf16x8 af[8];
#pragma unroll
  for (int kk = 0; kk < 8; ++kk)
    af[kk] = *reinterpret_cast<const bf16x8*>(A + (size_t)(rt * 8 + kk) * 512 + lane * 8);

  f32x4 acc0 = {0.f, 0.f, 0.f, 0.f};
  f32x4 acc1 = {0.f, 0.f, 0.f, 0.f};
  const int n16b = cb0 >> 4;
  const __bf16* __restrict__ Wp0 = W + (size_t)(n16b * 8) * 512 + lane * 8;
  const __bf16* __restrict__ Wp1 = W + (size_t)((n16b + 1) * 8) * 512 + lane * 8;

  bf16x8 ww[4];
  ww[0] = *reinterpret_cast<const bf16x8*>(Wp0);
  ww[1] = *reinterpret_cast<const bf16x8*>(Wp1);
  ww[2] = *reinterpret_cast<const bf16x8*>(Wp0 + 512);
  ww[3] = *reinterpret_cast<const bf16x8*>(Wp1 + 512);

#pragma unroll
  for (int kk = 0; kk < 8; ++kk) {
    const bf16x8 cw0 = ww[(2 * kk) & 3];
    const bf16x8 cw1 = ww[(2 * kk + 1) & 3];
    if (kk < 6) {
      ww[(2 * kk) & 3]     = *reinterpret_cast<const bf16x8*>(Wp0 + (size_t)(kk + 2) * 512);
      ww[(2 * kk + 1) & 3] = *reinterpret_cast<const bf16x8*>(Wp1 + (size_t)(kk + 2) * 512);
    }
    acc0 = __builtin_amdgcn_mfma_f32_16x16x32_bf16(cw0, af[kk], acc0, 0, 0, 0);
    acc1 = __builtin_amdgcn_mfma_f32_16x16x32_bf16(cw1, af[kk], acc1, 0, 0, 0);
  }

  const int token = m0 + l15;
  const f32x4 accs[2] = {acc0, acc1};

  if (mat < 2) {
    const float* __restrict__ bi = mat ? bk : bq;
    __bf16* __restrict__ dst = mat ? kfrag : qfrag;
#pragma unroll
    for (int nt = 0; nt < 2; ++nt) {
      const int e  = cb0 + nt * 16 + 4 * g;   // 4 consecutive dims r=0..3
      const float4 bb = *(const float4*)(bi + e);
      const int h  = e >> 5;
      const int gp = (e & 31) >> 3;
      const int ib = e & 7;                   // 4*(g&1)
      bf16x4 o;
      o.x = (__bf16)(accs[nt][0] + bb.x);
      o.y = (__bf16)(accs[nt][1] + bb.y);
      o.z = (__bf16)(accs[nt][2] + bb.z);
      o.w = (__bf16)(accs[nt][3] + bb.w);
      size_t idx;
      if (mat == 0) {
        const int lp = (token & 15) + 16 * gp;
        idx = ((size_t)(h * 256 + rt) * 64 + lp) * 8 + ib;
      } else {
        const int t  = token >> 6, tk = token & 63;
        const int mt = 2 * (tk >> 5) + ((tk >> 2) & 1);
        const int lp = 4 * ((tk >> 3) & 3) + (tk & 3) + 16 * gp;
        idx = ((size_t)((h * 64 + t) * 4 + mt) * 64 + lp) * 8 + ib;
      }
      *reinterpret_cast<bf16x4*>(dst + idx) = o;
    }
  } else {
    const int t  = token >> 6, tk = token & 63;
    const int ks = (tk >> 5) & 1;
    const int gp = (tk >> 3) & 3;
    const int i  = tk & 7;
#pragma unroll
    for (int nt = 0; nt < 2; ++nt) {
      const int e0 = cb0 + nt * 16 + 4 * g;
      const float4 bb = *(const float4*)(bv + e0);
      const float bbr[4] = {bb.x, bb.y, bb.z, bb.w};
#pragma unroll
      for (int r = 0; r < 4; ++r) {
        const int d  = e0 + r;
        const int h  = d >> 5, dh = (d >> 4) & 1;
        const size_t idx =
            ((size_t)(((h * 64 + t) * 2 + ks) * 2 + dh) * 64 + (d & 15) + 16 * gp) * 8 + i;
        vfrag[idx] = (__bf16)(accs[nt][r] + bbr[r]);
      }
    }
  }
}

// ---------------------------------------------------------------------------
// Fused attention + projection + residual + LayerNorm, fragment-major,
// 2-STAGE SOFTWARE PIPELINE + setprio.
// Block = 16 query rows, 512 threads = 8 waves, wave = head. Phase A is a
// barrier-free key loop whose 8 coalesced frag loads for tile t+1 are
// issued before tile t's MFMA/exp2 block (static A/B register sets). With
// the txn bottleneck gone (r12) the loop is latency-bound: this is the
// regime where the r9 pipeline (null when txn-bound) should pay.
// setprio(1) wraps MFMA clusters (waves here are phase-skewed, m191 regime).
// ---------------------------------------------------------------------------
#define LOADT(S, T)                                                            \
  {                                                                            \
    const __bf16* kb4 = kfrag + (size_t)(h * 64 + (T)) * 2048 + lane * 8;      \
    const __bf16* vb4 = vfrag + (size_t)(h * 64 + (T)) * 2048 + lane * 8;      \
    k##S##0 = *reinterpret_cast<const bf16x8*>(kb4);                           \
    k##S##1 = *reinterpret_cast<const bf16x8*>(kb4 + 512);                     \
    k##S##2 = *reinterpret_cast<const bf16x8*>(kb4 + 1024);                    \
    k##S##3 = *reinterpret_cast<const bf16x8*>(kb4 + 1536);                    \
    v##S##0 = *reinterpret_cast<const bf16x8*>(vb4);                           \
    v##S##1 = *reinterpret_cast<const bf16x8*>(vb4 + 512);                     \
    v##S##2 = *reinterpret_cast<const bf16x8*>(vb4 + 1024);                    \
    v##S##3 = *reinterpret_cast<const bf16x8*>(vb4 + 1536);                    \
  }

#define COMPUTE(S, T)                                                          \
  {                                                                            \
    const int j0c = (T) * 64;                                                  \
    const f32x4 z = {0.f, 0.f, 0.f, 0.f};                                      \
    __builtin_amdgcn_s_setprio(1);                                             \
    const f32x4 s0 = __builtin_amdgcn_mfma_f32_16x16x32_bf16(k##S##0, qf, z, 0, 0, 0); \
    const f32x4 s1 = __builtin_amdgcn_mfma_f32_16x16x32_bf16(k##S##1, qf, z, 0, 0, 0); \
    const f32x4 s2 = __builtin_amdgcn_mfma_f32_16x16x32_bf16(k##S##2, qf, z, 0, 0, 0); \
    const f32x4 s3 = __builtin_amdgcn_mfma_f32_16x16x32_bf16(k##S##3, qf, z, 0, 0, 0); \
    __builtin_amdgcn_s_setprio(0);                                             \
    bf16x8 pa0, pa1;                                                           \
    _Pragma("unroll")                                                          \
    for (int b_ = 0; b_ < 2; ++b_)                                             \
      _Pragma("unroll")                                                        \
      for (int r = 0; r < 4; ++r) {                                            \
        const int key0 = j0c + 8 * g + 4 * b_ + r;                             \
        const float e0 =                                                       \
            (key0 >= lo && key0 < hi) ? EXP2F((b_ ? s1[r] : s0[r]) * CL) : 0.f;\
        lsum += e0;                                                            \
        pa0[4 * b_ + r] = (__bf16)e0;                                          \
        const int key1 = key0 + 32;                                            \
        const float e1 =                                                       \
            (key1 >= lo && key1 < hi) ? EXP2F((b_ ? s3[r] : s2[r]) * CL) : 0.f;\
        lsum += e1;                                                            \
        pa1[4 * b_ + r] = (__bf16)e1;                                          \
      }                                                                        \
    __builtin_amdgcn_s_setprio(1);                                             \
    acc0 = __builtin_amdgcn_mfma_f32_16x16x32_bf16(pa0, v##S##0, acc0, 0, 0, 0); \
    acc1 = __builtin_amdgcn_mfma_f32_16x16x32_bf16(pa0, v##S##1, acc1, 0, 0, 0); \
    acc0 = __builtin_amdgcn_mfma_f32_16x16x32_bf16(pa1, v##S##2, acc0, 0, 0, 0); \
    acc1 = __builtin_amdgcn_mfma_f32_16x16x32_bf16(pa1, v##S##3, acc1, 0, 0, 0); \
    __builtin_amdgcn_s_setprio(0);                                             \
  }

__global__ __launch_bounds__(512) void attn_proj_ln(
    const __bf16* __restrict__ qfrag, const __bf16* __restrict__ kfrag,
    const __bf16* __restrict__ vfrag, const int* __restrict__ xb,
    const int* __restrict__ seg,
    const float* __restrict__ x, const __bf16* __restrict__ wofrag,
    const float* __restrict__ bo, const float* __restrict__ gamma,
    const float* __restrict__ beta, float* __restrict__ out)
{
  const int rt   = blockIdx.x;
  const int m0   = rt * 16;
  const int h    = threadIdx.x >> 6;    // wave = head
  const int lane = threadIdx.x & 63;
  const int l15  = lane & 15;
  const int g    = lane >> 4;
  const int qrow = m0 + l15;

  __shared__ __bf16 cl[16][264];        // ctx tile, padded stride
  __shared__ float redS[8][16];
  __shared__ float redQ[8][16];

  // ======== phase A: attention (2-stage pipelined, barrier-free) ========
  {
    const int b  = xb[qrow];
    const int lo = seg[b];
    const int hi = seg[b + 1];

    const bf16x8 qf = *reinterpret_cast<const bf16x8*>(
        qfrag + (size_t)(h * 256 + rt) * 512 + lane * 8);

    const int kstart = __shfl(lo, 0, 64);
    const int kend   = __shfl(hi, 15, 64);
    const int t0 = kstart >> 6;
    const int t1 = (kend + 63) >> 6;

    f32x4 acc0 = {0.f, 0.f, 0.f, 0.f};
    f32x4 acc1 = {0.f, 0.f, 0.f, 0.f};
    float lsum = 0.f;

    bf16x8 kA0, kA1, kA2, kA3, vA0, vA1, vA2, vA3;
    bf16x8 kB0, kB1, kB2, kB3, vB0, vB1, vB2, vB3;

    LOADT(A, t0)
    for (int t = t0; t < t1; t += 2) {
      const bool hasB = (t + 1 < t1);
      if (hasB) LOADT(B, t + 1)
      COMPUTE(A, t)
      if (hasB) {
        if (t + 2 < t1) LOADT(A, t + 2)
        COMPUTE(B, t + 1)
      }
    }

    lsum += __shfl_xor(lsum, 16, 64);
    lsum += __shfl_xor(lsum, 32, 64);
    const float inv = 1.0f / lsum;
    float invr[4];
#pragma unroll
    for (int r = 0; r < 4; ++r) invr[r] = __shfl(inv, 4 * g + r, 64);

#pragma unroll
    for (int r = 0; r < 4; ++r) {
      cl[4 * g + r][h * DH + l15]      = (__bf16)(acc0[r] * invr[r]);
      cl[4 * g + r][h * DH + 16 + l15] = (__bf16)(acc1[r] * invr[r]);
    }
  }
  __syncthreads();

  // ======== phase B: projection + residual + LayerNorm ========
  {
    bf16x8 af[8];
#pragma unroll
    for (int kk = 0; kk < 8; ++kk)
      af[kk] = *reinterpret_cast<const bf16x8*>(&cl[l15][kk * 32 + 8 * g]);

    f32x4 acc[2];
    acc[0] = f32x4{0.f, 0.f, 0.f, 0.f};
    acc[1] = f32x4{0.f, 0.f, 0.f, 0.f};

#pragma unroll
    for (int kk = 0; kk < 8; ++kk)
#pragma unroll
      for (int nt = 0; nt < 2; ++nt) {
        const bf16x8 wf = *reinterpret_cast<const bf16x8*>(
            wofrag + (size_t)((h * 2 + nt) * 8 + kk) * 512 + lane * 8);
        acc[nt] = __builtin_amdgcn_mfma_f32_16x16x32_bf16(af[kk], wf, acc[nt], 0, 0, 0);
      }

    float yv[2][4];
    float s1[4], s2[4];
#pragma unroll
    for (int r = 0; r < 4; ++r) { s1[r] = 0.f; s2[r] = 0.f; }
#pragma unroll
    for (int nt = 0; nt < 2; ++nt) {
      const int c = h * 32 + nt * 16 + l15;
      const float bb = bo[c];
#pragma unroll
      for (int r = 0; r < 4; ++r) {
        const int row = m0 + 4 * g + r;
        const float y = acc[nt][r] + bb + x[(size_t)row * E + c];
        yv[nt][r] = y;
        s1[r] += y;
        s2[r] += y * y;
      }
    }
#pragma unroll
    for (int off = 1; off < 16; off <<= 1) {
#pragma unroll
      for (int r = 0; r < 4; ++r) {
        s1[r] += __shfl_xor(s1[r], off, 64);
        s2[r] += __shfl_xor(s2[r], off, 64);
      }
    }
    if (l15 == 0) {
#pragma unroll
      for (int r = 0; r < 4; ++r) {
        redS[h][4 * g + r] = s1[r];
        redQ[h][4 * g + r] = s2[r];
      }
    }
    __syncthreads();
    float mu[4], rs[4];
#pragma unroll
    for (int r = 0; r < 4; ++r) {
      float ts = 0.f, tq = 0.f;
#pragma unroll
      for (int w = 0; w < 8; ++w) { ts += redS[w][4 * g + r]; tq += redQ[w][4 * g + r]; }
      mu[r] = ts * (1.0f / E);
      const float var = tq * (1.0f / E) - mu[r] * mu[r];
      rs[r] = rsqrtf(var + 1e-5f);
    }
#pragma unroll
    for (int nt = 0; nt < 2; ++nt) {
      const int c = h * 32 + nt * 16 + l15;
      const float gg = gamma[c];
      const float bt = beta[c];
#pragma unroll
      for (int r = 0; r < 4; ++r) {
        const int row = m0 + 4 * g + r;
        out[(size_t)row * E + c] = (yv[nt][r] - mu[r]) * rs[r] * gg + bt;
      }
    }
  }
}

}  // namespace

extern "C" void kernel_launch(void* const* d_in, const int* in_sizes, int n_in,
                              void* d_out, int out_size, void* d_ws, size_t ws_size,
                              hipStream_t stream) {
  const float* x     = (const float*)d_in[0];
  const float* pe    = (const float*)d_in[1];
  const int*   xb    = (const int*)d_in[2];
  const float* Wq    = (const float*)d_in[3];
  const float* Wk    = (const float*)d_in[4];
  const float* Wv    = (const float*)d_in[5];
  const float* bq    = (const float*)d_in[6];
  const float* bk    = (const float*)d_in[7];
  const float* bv    = (const float*)d_in[8];
  const float* Wo    = (const float*)d_in[9];
  const float* bo    = (const float*)d_in[10];
  const float* gamma = (const float*)d_in[11];
  const float* beta  = (const float*)d_in[12];
  float* out = (float*)d_out;

  __bf16* ws = (__bf16*)d_ws;
  const size_t NE = (size_t)N * E;          // 1,048,576 elements
  __bf16* qfrag = ws;                       // 2 MB
  __bf16* kfrag = ws + NE;                  // 2 MB
  __bf16* vfrag = ws + 2 * NE;              // 2 MB
  __bf16* xpef  = ws + 3 * NE;              // 2 MB
  __bf16* xvf   = ws + 4 * NE;              // 2 MB
  __bf16* wfrag = ws + 5 * NE;              // 512 KB (4 mats x 65536)
  int*    seg   = (int*)(ws + 5 * NE + 4 * 65536);

  prep_kernel<<<dim3(641), 256, 0, stream>>>(x, pe, xb, Wq, Wk, Wv, Wo,
                                             xpef, xvf, wfrag, seg);
  qkv_mfma<<<dim3(512, 3), 256, 0, stream>>>(xpef, xvf, wfrag, bq, bk, bv,
                                             qfrag, kfrag, vfrag);
  attn_proj_ln<<<dim3(256), 512, 0, stream>>>(qfrag, kfrag, vfrag, xb, seg,
                                              x, wfrag + 3 * 65536,
                                              bo, gamma, beta, out);
}

// Round 14
// 38.821 us; speedup vs baseline: 1.0226x; 1.0226x over previous
//
#include <hip/hip_runtime.h>
#include <math.h>

namespace {

constexpr int N  = 4096;
constexpr int E  = 256;
constexpr int H  = 8;
constexpr int DH = 32;
constexpr int BS = 8;
// fold 1/sqrt(DH) and log2(e): softmax in exp2 domain, no max subtraction
// (f32-safe: |s*CL| realistic max ~16, overflow at 127 -> 27 sigma margin)
constexpr float CL = 0.17677669529663687f * 1.4426950408889634f;

typedef __bf16 bf16x8 __attribute__((ext_vector_type(8)));
typedef __bf16 bf16x4 __attribute__((ext_vector_type(4)));
typedef float  f32x4  __attribute__((ext_vector_type(4)));

#if __has_builtin(__builtin_amdgcn_exp2f)
#define EXP2F(x) __builtin_amdgcn_exp2f(x)
#else
#define EXP2F(x) __expf((x) * 0.6931471805599453f)
#endif

__device__ inline bf16x8 pack8(float4 a, float4 b) {
  bf16x8 r;
  r[0] = (__bf16)a.x; r[1] = (__bf16)a.y; r[2] = (__bf16)a.z; r[3] = (__bf16)a.w;
  r[4] = (__bf16)b.x; r[5] = (__bf16)b.y; r[6] = (__bf16)b.z; r[7] = (__bf16)b.w;
  return r;
}

// ===========================================================================
// FRAGMENT-MAJOR LAYOUTS (proven round 12: 68.7 -> 38.5 us):
// every MFMA operand lives in memory as [frag][lane(64)][elem(8)] so the
// consuming wave loads it as ONE coalesced 1KB instruction (16B/lane).
//   xpe/xv : frag_id = rowtile(256)*8 + ktile(8)
//   wfrag  : per mat, frag_id = n16(16)*8 + ktile
//   qfrag  : frag_id = head*256 + rowtile
//   kfrag  : frag_id = (head*64 + keytile64)*4 + mt  (key-ID perm baked in)
//   vfrag  : frag_id = ((head*64+keytile64)*2+ks)*2+dh
// ===========================================================================

// ---------------------------------------------------------------------------
// prep: fragment-major bf16 conversion of x+pe, x, and the 4 weight mats.
// (frozen from round 12)
// ---------------------------------------------------------------------------
__global__ __launch_bounds__(256) void prep_kernel(
    const float* __restrict__ x, const float* __restrict__ pe,
    const int* __restrict__ xb,
    const float* __restrict__ Wq, const float* __restrict__ Wk,
    const float* __restrict__ Wv, const float* __restrict__ Wo,
    __bf16* __restrict__ xpef, __bf16* __restrict__ xvf,
    __bf16* __restrict__ wfrag, int* __restrict__ seg)
{
  const int bid  = blockIdx.x;
  const int wv4  = threadIdx.x >> 6;
  const int lane = threadIdx.x & 63;
  const int l15  = lane & 15, g = lane >> 4;

  if (bid < 512) {
    const int wid = bid * 4 + wv4;            // = rt*8 + kt
    const int rt = wid >> 3, kt = wid & 7;
    const float* xr = x  + (size_t)(rt * 16 + l15) * E + kt * 32 + 8 * g;
    const float* pr = pe + (size_t)(rt * 16 + l15) * E + kt * 32 + 8 * g;
    float4 a0 = *(const float4*)xr;
    float4 a1 = *(const float4*)(xr + 4);
    const float4 p0 = *(const float4*)pr;
    const float4 p1 = *(const float4*)(pr + 4);
    *reinterpret_cast<bf16x8*>(xvf + (size_t)wid * 512 + lane * 8) = pack8(a0, a1);
    a0.x += p0.x; a0.y += p0.y; a0.z += p0.z; a0.w += p0.w;
    a1.x += p1.x; a1.y += p1.y; a1.z += p1.z; a1.w += p1.w;
    *reinterpret_cast<bf16x8*>(xpef + (size_t)wid * 512 + lane * 8) = pack8(a0, a1);
  } else if (bid < 640) {
    const int wid = (bid - 512) * 4 + wv4;    // [0,512)
    const int mat = wid >> 7;
    const int rem = wid & 127;                // n16*8 + kt
    const int n16 = rem >> 3, kt = rem & 7;
    const float* __restrict__ W =
        (mat == 0) ? Wq : (mat == 1) ? Wk : (mat == 2) ? Wv : Wo;
    const float* wr = W + (size_t)(n16 * 16 + l15) * E + kt * 32 + 8 * g;
    *reinterpret_cast<bf16x8*>(wfrag + (size_t)wid * 512 + lane * 8) =
        pack8(*(const float4*)wr, *(const float4*)(wr + 4));
  } else {
    if (threadIdx.x <= BS) {
      const int t = threadIdx.x;
      int lo = 0, hi = N;
      while (lo < hi) { int mid = (lo + hi) >> 1; if (xb[mid] < t) lo = mid + 1; else hi = mid; }
      seg[t] = lo;
    }
  }
}

// ---------------------------------------------------------------------------
// MFMA QKV from fragment-major operands, A-reuse + W-window prefetch.
// Block = 16 rows x FULL 256 cols (grid (256,3)), 4 waves (64-col slices).
// The 8 A-fragments are loaded once per wave and reused for 32 MFMA
// (vs 16 in r12) -> total A-fragment loads halve chip-wide. W fragments
// stream through a 4-slot rotating window (loads stay in flight).
// 768 blocks -> 3 blocks/CU, 12 waves/CU.
// ---------------------------------------------------------------------------
__global__ __launch_bounds__(256) void qkv_mfma(
    const __bf16* __restrict__ xpef, const __bf16* __restrict__ xvf,
    const __bf16* __restrict__ wfrag,
    const float* __restrict__ bq, const float* __restrict__ bk,
    const float* __restrict__ bv,
    __bf16* __restrict__ qfrag, __bf16* __restrict__ kfrag,
    __bf16* __restrict__ vfrag)
{
  const int mat  = blockIdx.y;
  const int rt   = blockIdx.x;
  const int wv   = threadIdx.x >> 6;
  const int lane = threadIdx.x & 63;
  const int l15  = lane & 15, g = lane >> 4;
  const int m0   = rt * 16;

  const __bf16* __restrict__ A = (mat < 2) ? xpef : xvf;
  const __bf16* __restrict__ W = wfrag + (size_t)mat * 65536;

  bf16x8 af[8];
#pragma unroll
  for (int kk = 0; kk < 8; ++kk)
    af[kk] = *reinterpret_cast<const bf16x8*>(A + (size_t)(rt * 8 + kk) * 512 + lane * 8);

  const int token = m0 + l15;

#pragma unroll
  for (int p = 0; p < 2; ++p) {
    const int cb0  = wv * 64 + p * 32;
    const int n16b = cb0 >> 4;
    const __bf16* __restrict__ Wp0 = W + (size_t)(n16b * 8) * 512 + lane * 8;
    const __bf16* __restrict__ Wp1 = W + (size_t)((n16b + 1) * 8) * 512 + lane * 8;

    f32x4 acc0 = {0.f, 0.f, 0.f, 0.f};
    f32x4 acc1 = {0.f, 0.f, 0.f, 0.f};

    bf16x8 ww[4];
    ww[0] = *reinterpret_cast<const bf16x8*>(Wp0);
    ww[1] = *reinterpret_cast<const bf16x8*>(Wp1);
    ww[2] = *reinterpret_cast<const bf16x8*>(Wp0 + 512);
    ww[3] = *reinterpret_cast<const bf16x8*>(Wp1 + 512);

#pragma unroll
    for (int kk = 0; kk < 8; ++kk) {
      const bf16x8 cw0 = ww[(2 * kk) & 3];
      const bf16x8 cw1 = ww[(2 * kk + 1) & 3];
      if (kk < 6) {
        ww[(2 * kk) & 3]     = *reinterpret_cast<const bf16x8*>(Wp0 + (size_t)(kk + 2) * 512);
        ww[(2 * kk + 1) & 3] = *reinterpret_cast<const bf16x8*>(Wp1 + (size_t)(kk + 2) * 512);
      }
      acc0 = __builtin_amdgcn_mfma_f32_16x16x32_bf16(cw0, af[kk], acc0, 0, 0, 0);
      acc1 = __builtin_amdgcn_mfma_f32_16x16x32_bf16(cw1, af[kk], acc1, 0, 0, 0);
    }

    const f32x4 accs[2] = {acc0, acc1};
    if (mat < 2) {
      const float* __restrict__ bi = mat ? bk : bq;
      __bf16* __restrict__ dst = mat ? kfrag : qfrag;
#pragma unroll
      for (int nt = 0; nt < 2; ++nt) {
        const int e  = cb0 + nt * 16 + 4 * g;   // 4 consecutive dims r=0..3
        const float4 bb = *(const float4*)(bi + e);
        const int h  = e >> 5;
        const int gp = (e & 31) >> 3;
        const int ib = e & 7;                   // 4*(g&1)
        bf16x4 o;
        o.x = (__bf16)(accs[nt][0] + bb.x);
        o.y = (__bf16)(accs[nt][1] + bb.y);
        o.z = (__bf16)(accs[nt][2] + bb.z);
        o.w = (__bf16)(accs[nt][3] + bb.w);
        size_t idx;
        if (mat == 0) {
          const int lp = (token & 15) + 16 * gp;
          idx = ((size_t)(h * 256 + rt) * 64 + lp) * 8 + ib;
        } else {
          const int t  = token >> 6, tk = token & 63;
          const int mt = 2 * (tk >> 5) + ((tk >> 2) & 1);
          const int lp = 4 * ((tk >> 3) & 3) + (tk & 3) + 16 * gp;
          idx = ((size_t)((h * 64 + t) * 4 + mt) * 64 + lp) * 8 + ib;
        }
        *reinterpret_cast<bf16x4*>(dst + idx) = o;
      }
    } else {
      const int t  = token >> 6, tk = token & 63;
      const int ks = (tk >> 5) & 1;
      const int gp = (tk >> 3) & 3;
      const int i  = tk & 7;
#pragma unroll
      for (int nt = 0; nt < 2; ++nt) {
        const int e0 = cb0 + nt * 16 + 4 * g;
        const float4 bb = *(const float4*)(bv + e0);
        const float bbr[4] = {bb.x, bb.y, bb.z, bb.w};
#pragma unroll
        for (int r = 0; r < 4; ++r) {
          const int d  = e0 + r;
          const int h  = d >> 5, dh = (d >> 4) & 1;
          const size_t idx =
              ((size_t)(((h * 64 + t) * 2 + ks) * 2 + dh) * 64 + (d & 15) + 16 * gp) * 8 + i;
          vfrag[idx] = (__bf16)(accs[nt][r] + bbr[r]);
        }
      }
    }
  }
}

// ---------------------------------------------------------------------------
// Fused attention + projection + residual + LayerNorm, fragment-major.
// Block = 16 query rows, 512 threads = 8 waves, wave = head.
// Phase A: EXACT r12 free-running key loop (pipeline/setprio reverted —
//   r13 showed them null-to-negative). Wo fragments are hoisted into
//   registers BEFORE phase A: independent loads that complete under the
//   attention loop; __syncthreads prevents the compiler sinking them into
//   the phase-B tail (which they previously serialized).
// Phase B: proven proj+LN from LDS ctx + register Wo.
// ---------------------------------------------------------------------------
__global__ __launch_bounds__(512) void attn_proj_ln(
    const __bf16* __restrict__ qfrag, const __bf16* __restrict__ kfrag,
    const __bf16* __restrict__ vfrag, const int* __restrict__ xb,
    const int* __restrict__ seg,
    const float* __restrict__ x, const __bf16* __restrict__ wofrag,
    const float* __restrict__ bo, const float* __restrict__ gamma,
    const float* __restrict__ beta, float* __restrict__ out)
{
  const int rt   = blockIdx.x;
  const int m0   = rt * 16;
  const int h    = threadIdx.x >> 6;    // wave = head
  const int lane = threadIdx.x & 63;
  const int l15  = lane & 15;
  const int g    = lane >> 4;
  const int qrow = m0 + l15;

  __shared__ __bf16 cl[16][264];        // ctx tile, padded stride
  __shared__ float redS[8][16];
  __shared__ float redQ[8][16];

  // hoist phase-B Wo fragments (independent coalesced loads; complete
  // under phase A's compute instead of serializing the tail)
  bf16x8 wreg[2][8];
#pragma unroll
  for (int nt = 0; nt < 2; ++nt)
#pragma unroll
    for (int kk = 0; kk < 8; ++kk)
      wreg[nt][kk] = *reinterpret_cast<const bf16x8*>(
          wofrag + (size_t)((h * 2 + nt) * 8 + kk) * 512 + lane * 8);

  // ======== phase A: attention (exact r12) ========
  {
    const int b  = xb[qrow];
    const int lo = seg[b];
    const int hi = seg[b + 1];

    const bf16x8 qf = *reinterpret_cast<const bf16x8*>(
        qfrag + (size_t)(h * 256 + rt) * 512 + lane * 8);

    const int kstart = __shfl(lo, 0, 64);
    const int kend   = __shfl(hi, 15, 64);

    f32x4 acc0 = {0.f, 0.f, 0.f, 0.f};
    f32x4 acc1 = {0.f, 0.f, 0.f, 0.f};
    float lsum = 0.f;

    for (int t = kstart >> 6; t * 64 < kend; ++t) {
      const int j0 = t * 64;
      const __bf16* kb4 = kfrag + (size_t)(h * 64 + t) * 2048 + lane * 8;
      const __bf16* vb4 = vfrag + (size_t)(h * 64 + t) * 2048 + lane * 8;

      const bf16x8 kf0 = *reinterpret_cast<const bf16x8*>(kb4);
      const bf16x8 kf1 = *reinterpret_cast<const bf16x8*>(kb4 + 512);
      const bf16x8 kf2 = *reinterpret_cast<const bf16x8*>(kb4 + 1024);
      const bf16x8 kf3 = *reinterpret_cast<const bf16x8*>(kb4 + 1536);
      const bf16x8 vf00 = *reinterpret_cast<const bf16x8*>(vb4);          // ks0,dh0
      const bf16x8 vf01 = *reinterpret_cast<const bf16x8*>(vb4 + 512);    // ks0,dh1
      const bf16x8 vf10 = *reinterpret_cast<const bf16x8*>(vb4 + 1024);   // ks1,dh0
      const bf16x8 vf11 = *reinterpret_cast<const bf16x8*>(vb4 + 1536);   // ks1,dh1

      const f32x4 z = {0.f, 0.f, 0.f, 0.f};
      f32x4 s[4];
      s[0] = __builtin_amdgcn_mfma_f32_16x16x32_bf16(kf0, qf, z, 0, 0, 0);
      s[1] = __builtin_amdgcn_mfma_f32_16x16x32_bf16(kf1, qf, z, 0, 0, 0);
      s[2] = __builtin_amdgcn_mfma_f32_16x16x32_bf16(kf2, qf, z, 0, 0, 0);
      s[3] = __builtin_amdgcn_mfma_f32_16x16x32_bf16(kf3, qf, z, 0, 0, 0);

      bf16x8 pa[2];
#pragma unroll
      for (int ks = 0; ks < 2; ++ks)
#pragma unroll
        for (int b_ = 0; b_ < 2; ++b_)
#pragma unroll
          for (int r = 0; r < 4; ++r) {
            const int key = j0 + 32 * ks + 8 * g + 4 * b_ + r;
            const float sc = s[2 * ks + b_][r] * CL;
            const float e  = (key >= lo && key < hi) ? EXP2F(sc) : 0.f;
            lsum += e;
            pa[ks][4 * b_ + r] = (__bf16)e;
          }

      acc0 = __builtin_amdgcn_mfma_f32_16x16x32_bf16(pa[0], vf00, acc0, 0, 0, 0);
      acc1 = __builtin_amdgcn_mfma_f32_16x16x32_bf16(pa[0], vf01, acc1, 0, 0, 0);
      acc0 = __builtin_amdgcn_mfma_f32_16x16x32_bf16(pa[1], vf10, acc0, 0, 0, 0);
      acc1 = __builtin_amdgcn_mfma_f32_16x16x32_bf16(pa[1], vf11, acc1, 0, 0, 0);
    }

    lsum += __shfl_xor(lsum, 16, 64);
    lsum += __shfl_xor(lsum, 32, 64);
    const float inv = 1.0f / lsum;
    float invr[4];
#pragma unroll
    for (int r = 0; r < 4; ++r) invr[r] = __shfl(inv, 4 * g + r, 64);

#pragma unroll
    for (int r = 0; r < 4; ++r) {
      cl[4 * g + r][h * DH + l15]      = (__bf16)(acc0[r] * invr[r]);
      cl[4 * g + r][h * DH + 16 + l15] = (__bf16)(acc1[r] * invr[r]);
    }
  }
  __syncthreads();

  // ======== phase B: projection + residual + LayerNorm ========
  {
    bf16x8 af[8];
#pragma unroll
    for (int kk = 0; kk < 8; ++kk)
      af[kk] = *reinterpret_cast<const bf16x8*>(&cl[l15][kk * 32 + 8 * g]);

    f32x4 acc[2];
    acc[0] = f32x4{0.f, 0.f, 0.f, 0.f};
    acc[1] = f32x4{0.f, 0.f, 0.f, 0.f};

#pragma unroll
    for (int kk = 0; kk < 8; ++kk)
#pragma unroll
      for (int nt = 0; nt < 2; ++nt)
        acc[nt] = __builtin_amdgcn_mfma_f32_16x16x32_bf16(af[kk], wreg[nt][kk],
                                                          acc[nt], 0, 0, 0);

    float yv[2][4];
    float s1[4], s2[4];
#pragma unroll
    for (int r = 0; r < 4; ++r) { s1[r] = 0.f; s2[r] = 0.f; }
#pragma unroll
    for (int nt = 0; nt < 2; ++nt) {
      const int c = h * 32 + nt * 16 + l15;
      const float bb = bo[c];
#pragma unroll
      for (int r = 0; r < 4; ++r) {
        const int row = m0 + 4 * g + r;
        const float y = acc[nt][r] + bb + x[(size_t)row * E + c];
        yv[nt][r] = y;
        s1[r] += y;
        s2[r] += y * y;
      }
    }
#pragma unroll
    for (int off = 1; off < 16; off <<= 1) {
#pragma unroll
      for (int r = 0; r < 4; ++r) {
        s1[r] += __shfl_xor(s1[r], off, 64);
        s2[r] += __shfl_xor(s2[r], off, 64);
      }
    }
    if (l15 == 0) {
#pragma unroll
      for (int r = 0; r < 4; ++r) {
        redS[h][4 * g + r] = s1[r];
        redQ[h][4 * g + r] = s2[r];
      }
    }
    __syncthreads();
    float mu[4], rs[4];
#pragma unroll
    for (int r = 0; r < 4; ++r) {
      float ts = 0.f, tq = 0.f;
#pragma unroll
      for (int w = 0; w < 8; ++w) { ts += redS[w][4 * g + r]; tq += redQ[w][4 * g + r]; }
      mu[r] = ts * (1.0f / E);
      const float var = tq * (1.0f / E) - mu[r] * mu[r];
      rs[r] = rsqrtf(var + 1e-5f);
    }
#pragma unroll
    for (int nt = 0; nt < 2; ++nt) {
      const int c = h * 32 + nt * 16 + l15;
      const float gg = gamma[c];
      const float bt = beta[c];
#pragma unroll
      for (int r = 0; r < 4; ++r) {
        const int row = m0 + 4 * g + r;
        out[(size_t)row * E + c] = (yv[nt][r] - mu[r]) * rs[r] * gg + bt;
      }
    }
  }
}

}  // namespace

extern "C" void kernel_launch(void* const* d_in, const int* in_sizes, int n_in,
                              void* d_out, int out_size, void* d_ws, size_t ws_size,
                              hipStream_t stream) {
  const float* x     = (const float*)d_in[0];
  const float* pe    = (const float*)d_in[1];
  const int*   xb    = (const int*)d_in[2];
  const float* Wq    = (const float*)d_in[3];
  const float* Wk    = (const float*)d_in[4];
  const float* Wv    = (const float*)d_in[5];
  const float* bq    = (const float*)d_in[6];
  const float* bk    = (const float*)d_in[7];
  const float* bv    = (const float*)d_in[8];
  const float* Wo    = (const float*)d_in[9];
  const float* bo    = (const float*)d_in[10];
  const float* gamma = (const float*)d_in[11];
  const float* beta  = (const float*)d_in[12];
  float* out = (float*)d_out;

  __bf16* ws = (__bf16*)d_ws;
  const size_t NE = (size_t)N * E;          // 1,048,576 elements
  __bf16* qfrag = ws;                       // 2 MB
  __bf16* kfrag = ws + NE;                  // 2 MB
  __bf16* vfrag = ws + 2 * NE;              // 2 MB
  __bf16* xpef  = ws + 3 * NE;              // 2 MB
  __bf16* xvf   = ws + 4 * NE;              // 2 MB
  __bf16* wfrag = ws + 5 * NE;              // 512 KB (4 mats x 65536)
  int*    seg   = (int*)(ws + 5 * NE + 4 * 65536);

  prep_kernel<<<dim3(641), 256, 0, stream>>>(x, pe, xb, Wq, Wk, Wv, Wo,
                                             xpef, xvf, wfrag, seg);
  qkv_mfma<<<dim3(256, 3), 256, 0, stream>>>(xpef, xvf, wfrag, bq, bk, bv,
                                             qfrag, kfrag, vfrag);
  attn_proj_ln<<<dim3(256), 512, 0, stream>>>(qfrag, kfrag, vfrag, xb, seg,
                                              x, wfrag + 3 * 65536,
                                              bo, gamma, beta, out);
}